// Round 12
// baseline (1079.700 us; speedup 1.0000x reference)
//
#include <hip/hip_runtime.h>

typedef unsigned short u16;
typedef unsigned int u32;
typedef unsigned long long u64;
typedef signed char s8;
typedef __attribute__((ext_vector_type(8))) short bfrag8;
typedef __attribute__((ext_vector_type(4))) float f32x4;
typedef __attribute__((ext_vector_type(4))) int i32x4;
typedef __attribute__((address_space(1))) const void gconst_void;
typedef __attribute__((address_space(3))) void lds_void_t;

// ---------- helpers ----------
__device__ __forceinline__ float bf2f(u16 u) {
  return __uint_as_float(((u32)u) << 16);
}
__device__ __forceinline__ u16 f2bf(float f) {
  u32 u = __float_as_uint(f);
  u32 r = (u + 0x7FFFu + ((u >> 16) & 1u)) >> 16;  // RTNE
  return (u16)r;
}
__device__ __forceinline__ void split3(float v, u16& hi, u16& mi, u16& lo) {
  hi = f2bf(v); float r1 = v - bf2f(hi);
  mi = f2bf(r1); float r2 = r1 - bf2f(mi);
  lo = f2bf(r2);
}
__device__ __forceinline__ float ld1(const void* p, int isbf, long idx) {
  return isbf ? bf2f(((const u16*)p)[idx]) : ((const float*)p)[idx];
}
__device__ __forceinline__ void ld4(const void* p, int isbf, long base, long gc, long bound, float v[4]) {
  if (gc + 3 < bound && ((base & 3) == 0)) {
    if (isbf) {
      const ushort4 u = *(const ushort4*)((const u16*)p + base);
      v[0] = bf2f(u.x); v[1] = bf2f(u.y); v[2] = bf2f(u.z); v[3] = bf2f(u.w);
    } else {
      const float4 f = *(const float4*)((const float*)p + base);
      v[0] = f.x; v[1] = f.y; v[2] = f.z; v[3] = f.w;
    }
  } else {
    #pragma unroll
    for (int d = 0; d < 4; ++d) v[d] = (gc + d < bound) ? ld1(p, isbf, base + d) : 0.f;
  }
}

// ---------- input dtype autodetect ----------
__global__ void detect_k(const u32* __restrict__ a, long nw, int* __restrict__ flag) {
  long stride = (long)gridDim.x * 256;
  int f = 0;
  for (long j = (long)blockIdx.x * 256 + threadIdx.x; j < nw; j += stride) {
    u32 w = a[j];
    if (w == 0x00003F80u || w == 0x3F803F80u) f = 1;
  }
  if (__any(f)) {
    if ((threadIdx.x & 63) == 0) atomicOr(flag, 1);
  }
}

__device__ __forceinline__ int get_bf(int abf, const int* dtf) {
  return (abf >= 0) ? abf : *dtf;
}

// ---------- async global->LDS stage ----------
__device__ __forceinline__ void stageB16(const void* g, void* lds) {
#if __has_builtin(__builtin_amdgcn_global_load_lds)
  __builtin_amdgcn_global_load_lds((gconst_void*)g, (lds_void_t*)lds, 16, 0, 0);
#else
  int lane = threadIdx.x & 63;
  *(int4*)((char*)lds + lane * 16) = *(const int4*)g;
#endif
}

// ---------- i8 triangle SYRK -> bf16 planes + f64 row sums ----------
__global__ __launch_bounds__(256) void syrk_tri_i8(
    const s8* __restrict__ Ag, int ldk, int ldc, int K,
    u16* __restrict__ Ah, u16* __restrict__ Al, double* __restrict__ rsum)
{
  __shared__ s8 At[128 * 64];
  __shared__ s8 Bt[128 * 64];
  __shared__ int tb[4][16][17];
  const int t = blockIdx.x;
  int ti = (int)((sqrtf((float)(8 * t + 1)) - 1.0f) * 0.5f);
  while ((ti + 1) * (ti + 2) / 2 <= t) ++ti;
  while (ti * (ti + 1) / 2 > t) --ti;
  const int tj = t - ti * (ti + 1) / 2;

  const int tid = threadIdx.x;
  const int wave = tid >> 6, lane = tid & 63;
  const int wr = wave >> 1, wc = wave & 1;
  const long rowA0 = (long)ti * 128;
  const long rowB0 = (long)tj * 128;

  i32x4 acc[4][4];
  #pragma unroll
  for (int i = 0; i < 4; ++i)
    #pragma unroll
    for (int j = 0; j < 4; ++j) acc[i][j] = (i32x4)0;

  const int srow = lane >> 2;
  const int scol = (lane & 3) * 16;
  const int m = lane & 15, q = lane >> 4;

  for (int k0 = 0; k0 < K; k0 += 64) {
    #pragma unroll
    for (int tt = 0; tt < 2; ++tt) {
      const int r = wave * 32 + tt * 16;
      stageB16(Ag + (rowA0 + r + srow) * (long)ldk + k0 + scol, At + r * 64);
      stageB16(Ag + (rowB0 + r + srow) * (long)ldk + k0 + scol, Bt + r * 64);
    }
    __syncthreads();

    i32x4 af[4], bf[4];
    #pragma unroll
    for (int mt = 0; mt < 4; ++mt)
      af[mt] = *(const i32x4*)(At + (wr * 64 + mt * 16 + m) * 64 + q * 16);
    #pragma unroll
    for (int nt = 0; nt < 4; ++nt)
      bf[nt] = *(const i32x4*)(Bt + (wc * 64 + nt * 16 + m) * 64 + q * 16);
    #pragma unroll
    for (int mt = 0; mt < 4; ++mt)
      #pragma unroll
      for (int nt = 0; nt < 4; ++nt)
        acc[mt][nt] = __builtin_amdgcn_mfma_i32_16x16x64_i8(af[mt], bf[nt], acc[mt][nt], 0, 0, 0);
    __syncthreads();
  }

  #pragma unroll
  for (int mt = 0; mt < 4; ++mt) {
    double rp[4] = {0.0, 0.0, 0.0, 0.0};
    #pragma unroll
    for (int nt = 0; nt < 4; ++nt) {
      const long gr0 = rowA0 + wr * 64 + mt * 16 + q * 4;
      const long gc = rowB0 + wc * 64 + nt * 16 + m;
      #pragma unroll
      for (int r = 0; r < 4; ++r) {
        const long gr = gr0 + r;
        int iv = (gr == gc) ? 0 : acc[mt][nt][r];
        float fv = (float)iv;
        long idx = gr * ldc + gc;
        u16 h = f2bf(fv);
        Ah[idx] = h;
        if (Al) Al[idx] = f2bf(fv - bf2f(h));
        rp[r] += (double)iv;
      }
    }
    #pragma unroll
    for (int r = 0; r < 4; ++r) {
      double v = rp[r];
      for (int off = 8; off > 0; off >>= 1) v += __shfl_down(v, off);
      if (m == 0) atomicAdd(&rsum[rowA0 + wr * 64 + mt * 16 + q * 4 + r], v);
    }
  }
  if (ti != tj) {
    #pragma unroll
    for (int nt = 0; nt < 4; ++nt) {
      double cp = 0.0;
      #pragma unroll
      for (int mt = 0; mt < 4; ++mt) {
        #pragma unroll
        for (int r = 0; r < 4; ++r) tb[wave][q * 4 + r][m] = acc[mt][nt][r];
        const long baseR = rowB0 + wc * 64 + nt * 16;
        const long baseC = rowA0 + wr * 64 + mt * 16;
        #pragma unroll
        for (int r = 0; r < 4; ++r) {
          float tv = (float)tb[wave][m][q * 4 + r];
          long idx = (baseR + q * 4 + r) * ldc + baseC + m;
          u16 h = f2bf(tv);
          Ah[idx] = h;
          if (Al) Al[idx] = f2bf(tv - bf2f(h));
        }
        #pragma unroll
        for (int r = 0; r < 4; ++r) cp += (double)acc[mt][nt][r];
      }
      double v = cp;
      v += __shfl_down(v, 32);
      v += __shfl_down(v, 16);
      if (q == 0) atomicAdd(&rsum[rowB0 + wc * 64 + nt * 16 + m], v);
    }
  }
}

// ---------- bf16 2-plane triangle SYRK, K-split parts (L3) ----------
__global__ __launch_bounds__(256) void syrk_tri2_parts(
    const u16* __restrict__ Ah, const u16* __restrict__ Al, int ldk,
    float* __restrict__ parts, int n, int per)
{
  __shared__ u16 Ath[128 * 32];
  __shared__ u16 Bth[128 * 32];
  __shared__ u16 Atl[128 * 32];
  __shared__ u16 Btl[128 * 32];
  const int t = blockIdx.x;
  int ti = (int)((sqrtf((float)(8 * t + 1)) - 1.0f) * 0.5f);
  while ((ti + 1) * (ti + 2) / 2 <= t) ++ti;
  while (ti * (ti + 1) / 2 > t) --ti;
  const int tj = t - ti * (ti + 1) / 2;

  const int tid = threadIdx.x;
  const int wave = tid >> 6, lane = tid & 63;
  const int wr = wave >> 1, wc = wave & 1;
  const long rowA0 = (long)ti * 128;
  const long rowB0 = (long)tj * 128;
  const int kbeg = blockIdx.y * per;
  const int kend = kbeg + per;

  f32x4 acc[4][4];
  #pragma unroll
  for (int i = 0; i < 4; ++i)
    #pragma unroll
    for (int j = 0; j < 4; ++j) acc[i][j] = (f32x4)0.f;

  const int srow = lane >> 2;
  const int scol = (lane & 3) * 8;
  const int m = lane & 15, q = lane >> 4;

  for (int k0 = kbeg; k0 < kend; k0 += 32) {
    #pragma unroll
    for (int tt = 0; tt < 2; ++tt) {
      const int r = wave * 32 + tt * 16;
      stageB16(Ah + (rowA0 + r + srow) * (long)ldk + k0 + scol, Ath + r * 32);
      stageB16(Ah + (rowB0 + r + srow) * (long)ldk + k0 + scol, Bth + r * 32);
      stageB16(Al + (rowA0 + r + srow) * (long)ldk + k0 + scol, Atl + r * 32);
      stageB16(Al + (rowB0 + r + srow) * (long)ldk + k0 + scol, Btl + r * 32);
    }
    __syncthreads();

    bfrag8 afh[4], afl[4], bfh[4], bfl[4];
    #pragma unroll
    for (int mt = 0; mt < 4; ++mt) {
      afh[mt] = *(const bfrag8*)(Ath + (wr * 64 + mt * 16 + m) * 32 + q * 8);
      afl[mt] = *(const bfrag8*)(Atl + (wr * 64 + mt * 16 + m) * 32 + q * 8);
    }
    #pragma unroll
    for (int nt = 0; nt < 4; ++nt) {
      bfh[nt] = *(const bfrag8*)(Bth + (wc * 64 + nt * 16 + m) * 32 + q * 8);
      bfl[nt] = *(const bfrag8*)(Btl + (wc * 64 + nt * 16 + m) * 32 + q * 8);
    }
    #pragma unroll
    for (int mt = 0; mt < 4; ++mt)
      #pragma unroll
      for (int nt = 0; nt < 4; ++nt) {
        acc[mt][nt] = __builtin_amdgcn_mfma_f32_16x16x32_bf16(afh[mt], bfh[nt], acc[mt][nt], 0, 0, 0);
        acc[mt][nt] = __builtin_amdgcn_mfma_f32_16x16x32_bf16(afh[mt], bfl[nt], acc[mt][nt], 0, 0, 0);
        acc[mt][nt] = __builtin_amdgcn_mfma_f32_16x16x32_bf16(afl[mt], bfh[nt], acc[mt][nt], 0, 0, 0);
        acc[mt][nt] = __builtin_amdgcn_mfma_f32_16x16x32_bf16(afl[mt], bfl[nt], acc[mt][nt], 0, 0, 0);
      }
    __syncthreads();
  }

  float* P = parts + (long)blockIdx.y * n * n;
  #pragma unroll
  for (int mt = 0; mt < 4; ++mt) {
    #pragma unroll
    for (int nt = 0; nt < 4; ++nt) {
      const long gr0 = rowA0 + wr * 64 + mt * 16 + q * 4;
      const long gc = rowB0 + wc * 64 + nt * 16 + m;
      #pragma unroll
      for (int r = 0; r < 4; ++r)
        P[(gr0 + r) * n + gc] = acc[mt][nt][r];
    }
  }
}

// sum nz parts, mirror, zero diag; Ah/Al write + f64 row sums.
__global__ void reduce_tri_mirror_k(const float* __restrict__ parts,
                                    u16* __restrict__ Ah, u16* __restrict__ Al,
                                    double* __restrict__ rsum, int n, int nz) {
  __shared__ double red[256];
  const int tid = threadIdx.x;
  long idx = (long)blockIdx.x * 256 + tid;
  long nn = (long)n * n;
  long r = idx / n, c = idx - r * n;
  double myv = 0.0;
  if (idx < nn) {
    if (r == c) {
      Ah[idx] = 0; Al[idx] = 0;
    } else if (r > c) {
      float s = 0.f;
      for (int z = 0; z < nz; ++z) s += parts[(long)z * nn + r * n + c];
      long mi = c * n + r;
      u16 h = f2bf(s);
      u16 l = f2bf(s - bf2f(h));
      Ah[idx] = h; Al[idx] = l;
      Ah[mi] = h;  Al[mi] = l;
      myv = (double)s;
      atomicAdd(&rsum[c], (double)s);
    }
  }
  red[tid] = myv;
  __syncthreads();
  for (int st = 128; st > 0; st >>= 1) {
    if (tid < st) red[tid] += red[tid + st];
    __syncthreads();
  }
  if (tid == 0 && idx < nn) atomicAdd(&rsum[r], red[0]);
}

// ---------- fused build (i8 augment operand) + gather-x (3-plane XP) ----------
__global__ void bg_i8_k(const void* __restrict__ src, int srcbf, int nsrc,
                        const int* __restrict__ perm, int kRows,
                        s8* __restrict__ Ag, const int* __restrict__ dtf,
                        const float* __restrict__ xsrc, const float* __restrict__ score,
                        u16* __restrict__ XP, unsigned nbB) {
  if (blockIdx.x < nbB) {
    long tot = (long)kRows * nsrc;
    long idx = (long)blockIdx.x * 256 + threadIdx.x;
    if (idx >= tot) return;
    int r = (int)(idx / nsrc);
    int c = (int)(idx - (long)r * nsrc);
    int p = perm[r];
    float v = ld1(src, get_bf(srcbf, dtf), (long)p * nsrc + c);
    if (c == p) v += 1.f;
    Ag[idx] = (s8)(int)v;
  } else {
    long tot = (long)kRows * 224;
    long idx = (long)(blockIdx.x - nbB) * 256 + threadIdx.x;
    if (idx >= tot) return;
    int r = (int)(idx / 224);
    int c = (int)(idx - (long)r * 224);
    float v = 0.f;
    if (c < 200) {
      int p = perm[r];
      v = xsrc[(long)p * 200 + c] * score[p];
    }
    u16 h, mi, lo; split3(v, h, mi, lo);
    long pitch = (long)kRows * 224;
    XP[idx] = h; XP[pitch + idx] = mi; XP[2 * pitch + idx] = lo;
  }
}

// fused build (2-plane bf16 from Ah2/Al2) + gather-x (3-plane XP)
__global__ void bg_sp_k(const u16* __restrict__ srcH, const u16* __restrict__ srcL,
                        int nsrc, const int* __restrict__ perm, int kRows,
                        u16* __restrict__ Agh, u16* __restrict__ Agl,
                        const float* __restrict__ xsrc, const float* __restrict__ score,
                        u16* __restrict__ XP, unsigned nbB) {
  if (blockIdx.x < nbB) {
    long tot = (long)kRows * nsrc;
    long idx = (long)blockIdx.x * 256 + threadIdx.x;
    if (idx >= tot) return;
    int r = (int)(idx / nsrc);
    int c = (int)(idx - (long)r * nsrc);
    int p = perm[r];
    long si = (long)p * nsrc + c;
    float v = bf2f(srcH[si]) + bf2f(srcL[si]);
    if (c == p) v += 1.f;
    u16 h = f2bf(v);
    Agh[idx] = h;
    Agl[idx] = f2bf(v - bf2f(h));
  } else {
    long tot = (long)kRows * 224;
    long idx = (long)(blockIdx.x - nbB) * 256 + threadIdx.x;
    if (idx >= tot) return;
    int r = (int)(idx / 224);
    int c = (int)(idx - (long)r * 224);
    float v = 0.f;
    if (c < 200) {
      int p = perm[r];
      v = xsrc[(long)p * 200 + c] * score[p];
    }
    u16 h, mi, lo; split3(v, h, mi, lo);
    long pitch = (long)kRows * 224;
    XP[idx] = h; XP[pitch + idx] = mi; XP[2 * pitch + idx] = lo;
  }
}

// ---------- MFMA aggregation: Y = A @ Z ----------
template<int NT>
__global__ __launch_bounds__(256) void agg_mfma(
    const u16* __restrict__ Ah, const u16* __restrict__ Al,
    const u16* __restrict__ ZT, float* __restrict__ parts,
    int K, int per_steps)
{
  __shared__ u16 At[128 * 32];
  __shared__ u16 Alt[128 * 32];
  __shared__ u16 Zt[3 * NT * 512];
  const int tid = threadIdx.x;
  const int wave = tid >> 6, lane = tid & 63;
  const long row0 = (long)blockIdx.x * 128;
  const int chunk = blockIdx.y;
  const int kbeg = chunk * per_steps * 32;
  const int kend = min(K, kbeg + per_steps * 32);
  const int m = lane & 15, q = lane >> 4;
  const int srow = lane >> 2, scol = (lane & 3) * 8;
  const bool hasAl = (Al != nullptr);

  f32x4 acc[2][NT];
  #pragma unroll
  for (int rt = 0; rt < 2; ++rt)
    #pragma unroll
    for (int ct = 0; ct < NT; ++ct) acc[rt][ct] = (f32x4)0.f;

  for (int k0 = kbeg; k0 < kend; k0 += 32) {
    #pragma unroll
    for (int t = 0; t < 2; ++t) {
      const int r = wave * 32 + t * 16;
      stageB16(Ah + (row0 + r + srow) * (long)K + k0 + scol, At + r * 32);
      if (hasAl)
        stageB16(Al + (row0 + r + srow) * (long)K + k0 + scol, Alt + r * 32);
    }
    for (int s = wave; s < 3 * NT; s += 4) {
      const u16* g = ZT + ((long)(s * 16 + srow)) * K + k0 + scol;
      stageB16(g, Zt + s * 512);
    }
    __syncthreads();

    bfrag8 af0 = *(const bfrag8*)(At + (wave * 32 + m) * 32 + q * 8);
    bfrag8 af1 = *(const bfrag8*)(At + (wave * 32 + 16 + m) * 32 + q * 8);
    bfrag8 al0, al1;
    if (hasAl) {
      al0 = *(const bfrag8*)(Alt + (wave * 32 + m) * 32 + q * 8);
      al1 = *(const bfrag8*)(Alt + (wave * 32 + 16 + m) * 32 + q * 8);
    }
    #pragma unroll
    for (int ct = 0; ct < NT; ++ct) {
      bfrag8 b0 = *(const bfrag8*)(Zt + (0 * NT + ct) * 512 + m * 32 + q * 8);
      bfrag8 b1 = *(const bfrag8*)(Zt + (1 * NT + ct) * 512 + m * 32 + q * 8);
      bfrag8 b2 = *(const bfrag8*)(Zt + (2 * NT + ct) * 512 + m * 32 + q * 8);
      acc[0][ct] = __builtin_amdgcn_mfma_f32_16x16x32_bf16(af0, b0, acc[0][ct], 0, 0, 0);
      acc[0][ct] = __builtin_amdgcn_mfma_f32_16x16x32_bf16(af0, b1, acc[0][ct], 0, 0, 0);
      acc[0][ct] = __builtin_amdgcn_mfma_f32_16x16x32_bf16(af0, b2, acc[0][ct], 0, 0, 0);
      acc[1][ct] = __builtin_amdgcn_mfma_f32_16x16x32_bf16(af1, b0, acc[1][ct], 0, 0, 0);
      acc[1][ct] = __builtin_amdgcn_mfma_f32_16x16x32_bf16(af1, b1, acc[1][ct], 0, 0, 0);
      acc[1][ct] = __builtin_amdgcn_mfma_f32_16x16x32_bf16(af1, b2, acc[1][ct], 0, 0, 0);
      if (hasAl) {
        acc[0][ct] = __builtin_amdgcn_mfma_f32_16x16x32_bf16(al0, b0, acc[0][ct], 0, 0, 0);
        acc[0][ct] = __builtin_amdgcn_mfma_f32_16x16x32_bf16(al0, b1, acc[0][ct], 0, 0, 0);
        acc[1][ct] = __builtin_amdgcn_mfma_f32_16x16x32_bf16(al1, b0, acc[1][ct], 0, 0, 0);
        acc[1][ct] = __builtin_amdgcn_mfma_f32_16x16x32_bf16(al1, b1, acc[1][ct], 0, 0, 0);
      }
    }
    __syncthreads();
  }

  float* P = parts + (long)chunk * gridDim.x * 128 * (NT * 16);
  #pragma unroll
  for (int rt = 0; rt < 2; ++rt) {
    #pragma unroll
    for (int ct = 0; ct < NT; ++ct) {
      const long grow0 = row0 + wave * 32 + rt * 16 + q * 4;
      const long gcol = ct * 16 + m;
      #pragma unroll
      for (int r = 0; r < 4; ++r)
        P[(grow0 + r) * (NT * 16) + gcol] = acc[rt][ct][r];
    }
  }
}

// fused: reduce parts + GCN epilogue (+ optional pooling score)
__global__ __launch_bounds__(256) void reduce_epi_k(
    const float* __restrict__ parts, const float* __restrict__ Zs,
    const double* __restrict__ rs, const float* __restrict__ b,
    float* __restrict__ out, int n, int nz, int relu,
    const float* __restrict__ pw, float* __restrict__ score)
{
  __shared__ float vrow[200];
  const int i = blockIdx.x, tid = threadIdx.x;
  float dv = (float)(1.0 / sqrt(rs[i] + 2.0));
  if (tid < 200) {
    long base = (long)i * 208 + tid;
    float s = 0.f;
    for (int c = 0; c < nz; ++c) s += parts[(long)c * n * 208 + base];
    float v = dv * (s + 2.f * Zs[(long)i * 200 + tid]) + b[tid];
    if (relu) v = fmaxf(v, 0.f);
    out[(long)i * 200 + tid] = v;
    if (score) vrow[tid] = v;
  }
  if (!score) return;
  __syncthreads();
  if (tid < 64) {
    double ps = 0.0;
    for (int j = tid; j < 200; j += 64) { double w = pw[j]; ps += w * w; }
    for (int off = 32; off > 0; off >>= 1) ps += __shfl_down(ps, off);
    double nrm = sqrt(__shfl(ps, 0));
    double s = 0.0;
    for (int j = tid; j < 200; j += 64) s += (double)vrow[j] * (double)pw[j];
    for (int off = 32; off > 0; off >>= 1) s += __shfl_down(s, off);
    if (tid == 0) score[i] = (float)tanh(s / nrm);
  }
}

// fused adj->bf16 plane + row sums (level 0)
__global__ void a_from_adj_rs_k(const void* __restrict__ adj, const int* __restrict__ dtf,
                                int n, u16* __restrict__ Ah, double* __restrict__ rs) {
  __shared__ double red[256];
  int bf = *dtf;
  const int row = blockIdx.x, tid = threadIdx.x;
  const long base = (long)row * n;
  double s = 0.0;
  for (int j = tid; j < n; j += 256) {
    float v = ld1(adj, bf, base + j);
    Ah[base + j] = bf ? ((const u16*)adj)[base + j] : f2bf(v);
    s += (double)v;
  }
  red[tid] = s; __syncthreads();
  for (int st = 128; st > 0; st >>= 1) {
    if (tid < st) red[tid] += red[tid + st];
    __syncthreads();
  }
  if (tid == 0) rs[row] = red[0];
}

// ---------- MFMA x@W (3-plane x, 3-plane W^T, 6 cross terms) + dinv + ZT emit ----------
__global__ __launch_bounds__(256) void gemm_xw_mfma(
    const u16* __restrict__ XP, const u16* __restrict__ WTP,
    const double* __restrict__ rs, float* __restrict__ Z, u16* __restrict__ ZT, int n)
{
  __shared__ u16 At[3 * 128 * 32];
  __shared__ u16 Bt[39 * 512];
  const int tid = threadIdx.x;
  const int wave = tid >> 6, lane = tid & 63;
  const long row0 = (long)blockIdx.x * 128;
  const int m = lane & 15, q = lane >> 4;
  const int srow = lane >> 2, scol = (lane & 3) * 8;
  const long xpitch = (long)n * 224;

  f32x4 acc[2][13];
  #pragma unroll
  for (int rt = 0; rt < 2; ++rt)
    #pragma unroll
    for (int ct = 0; ct < 13; ++ct) acc[rt][ct] = (f32x4)0.f;

  for (int k0 = 0; k0 < 224; k0 += 32) {
    #pragma unroll
    for (int t = 0; t < 2; ++t) {
      const int r = wave * 32 + t * 16;
      #pragma unroll
      for (int p = 0; p < 3; ++p)
        stageB16(XP + p * xpitch + (row0 + r + srow) * 224 + k0 + scol,
                 At + p * 4096 + r * 32);
    }
    for (int s = wave; s < 39; s += 4) {
      int p = s / 13, t = s % 13;
      stageB16(WTP + ((long)(p * 208 + t * 16 + srow)) * 224 + k0 + scol, Bt + s * 512);
    }
    __syncthreads();

    bfrag8 af[2][3];
    #pragma unroll
    for (int rt = 0; rt < 2; ++rt)
      #pragma unroll
      for (int p = 0; p < 3; ++p)
        af[rt][p] = *(const bfrag8*)(At + p * 4096 + (wave * 32 + rt * 16 + m) * 32 + q * 8);
    #pragma unroll
    for (int ct = 0; ct < 13; ++ct) {
      bfrag8 b0 = *(const bfrag8*)(Bt + (0 * 13 + ct) * 512 + m * 32 + q * 8);
      bfrag8 b1 = *(const bfrag8*)(Bt + (1 * 13 + ct) * 512 + m * 32 + q * 8);
      bfrag8 b2 = *(const bfrag8*)(Bt + (2 * 13 + ct) * 512 + m * 32 + q * 8);
      #pragma unroll
      for (int rt = 0; rt < 2; ++rt) {
        acc[rt][ct] = __builtin_amdgcn_mfma_f32_16x16x32_bf16(af[rt][0], b0, acc[rt][ct], 0, 0, 0);
        acc[rt][ct] = __builtin_amdgcn_mfma_f32_16x16x32_bf16(af[rt][0], b1, acc[rt][ct], 0, 0, 0);
        acc[rt][ct] = __builtin_amdgcn_mfma_f32_16x16x32_bf16(af[rt][1], b0, acc[rt][ct], 0, 0, 0);
        acc[rt][ct] = __builtin_amdgcn_mfma_f32_16x16x32_bf16(af[rt][0], b2, acc[rt][ct], 0, 0, 0);
        acc[rt][ct] = __builtin_amdgcn_mfma_f32_16x16x32_bf16(af[rt][2], b0, acc[rt][ct], 0, 0, 0);
        acc[rt][ct] = __builtin_amdgcn_mfma_f32_16x16x32_bf16(af[rt][1], b1, acc[rt][ct], 0, 0, 0);
      }
    }
    __syncthreads();
  }

  #pragma unroll
  for (int rt = 0; rt < 2; ++rt) {
    #pragma unroll
    for (int ct = 0; ct < 13; ++ct) {
      const long gc = ct * 16 + m;
      if (gc >= 200) continue;
      #pragma unroll
      for (int r = 0; r < 4; ++r) {
        const long gr = row0 + wave * 32 + rt * 16 + q * 4 + r;
        float dv = (float)(1.0 / sqrt(rs[gr] + 2.0));
        float v = acc[rt][ct][r] * dv;
        Z[gr * 200 + gc] = v;
        u16 hi, mi, lo; split3(v, hi, mi, lo);
        ZT[((long)0 * 208 + gc) * n + gr] = hi;
        ZT[((long)1 * 208 + gc) * n + gr] = mi;
        ZT[((long)2 * 208 + gc) * n + gr] = lo;
      }
    }
  }
}

// W (200x200 f32) -> W^T 3-plane bf16, 208x224 padded; 5 weights via by-value struct
struct WPtrs { const float* w[5]; };

__global__ void wsplit_k(WPtrs ws, u16* __restrict__ WTP) {
  int w = blockIdx.y;
  long idx = (long)blockIdx.x * 256 + threadIdx.x;
  if (idx >= 208 * 224) return;
  int nrow = (int)(idx / 224);
  int kcol = (int)(idx - (long)nrow * 224);
  float v = (nrow < 200 && kcol < 200) ? ws.w[w][(long)kcol * 200 + nrow] : 0.f;
  u16 hi, mi, lo; split3(v, hi, mi, lo);
  u16* base = WTP + (long)w * 3 * 208 * 224;
  base[idx] = hi;
  base[208 * 224 + idx] = mi;
  base[2 * 208 * 224 + idx] = lo;
}

// ---------- fp64 GEMM (gcn0 x@W with K=3, and final x@u2w) ----------
__global__ __launch_bounds__(256) void gemm64_f64(
    const void* __restrict__ Ap, long lda, int abf,
    const void* __restrict__ Bp, long ldb, int bbf,
    float* __restrict__ C, long ldc, int M, int N, int K,
    const double* __restrict__ rsum, u16* __restrict__ ZT, const int* __restrict__ dtf)
{
  const int abf_ = get_bf(abf, dtf);
  const int bbf_ = get_bf(bbf, dtf);
  __shared__ float As[16][64];
  __shared__ float Bs[16][64];
  const int tid = threadIdx.x;
  const int tr = tid >> 4, tc = tid & 15;
  const long row0 = (long)blockIdx.y * 64;
  const long col0 = (long)blockIdx.x * 64;
  double acc[4][4];
  #pragma unroll
  for (int i = 0; i < 4; ++i)
    #pragma unroll
    for (int j = 0; j < 4; ++j) acc[i][j] = 0.0;

  const int am = tid >> 2;
  const int ak = (tid & 3) * 4;
  const int bk = tid >> 4;
  const int bn = (tid & 15) * 4;

  for (int k0 = 0; k0 < K; k0 += 16) {
    float va[4] = {0.f, 0.f, 0.f, 0.f};
    {
      long gm = row0 + am; long gk = k0 + ak;
      if (gm < M && gk < K) ld4(Ap, abf_, gm * lda + gk, gk, K, va);
    }
    As[ak + 0][am] = va[0]; As[ak + 1][am] = va[1];
    As[ak + 2][am] = va[2]; As[ak + 3][am] = va[3];

    float vb[4] = {0.f, 0.f, 0.f, 0.f};
    {
      long gk = k0 + bk; long gn = col0 + bn;
      if (gk < K && gn < N) ld4(Bp, bbf_, gk * ldb + gn, gn, N, vb);
    }
    Bs[bk][bn + 0] = vb[0]; Bs[bk][bn + 1] = vb[1];
    Bs[bk][bn + 2] = vb[2]; Bs[bk][bn + 3] = vb[3];

    __syncthreads();
    #pragma unroll
    for (int kk = 0; kk < 16; ++kk) {
      float a[4], b[4];
      #pragma unroll
      for (int i = 0; i < 4; ++i) a[i] = As[kk][tr * 4 + i];
      #pragma unroll
      for (int j = 0; j < 4; ++j) b[j] = Bs[kk][tc * 4 + j];
      #pragma unroll
      for (int i = 0; i < 4; ++i)
        #pragma unroll
        for (int j = 0; j < 4; ++j)
          acc[i][j] += (double)a[i] * (double)b[j];
    }
    __syncthreads();
  }
  #pragma unroll
  for (int i = 0; i < 4; ++i) {
    long gm = row0 + tr * 4 + i;
    if (gm >= M) continue;
    float sc = rsum ? (float)(1.0 / sqrt(rsum[gm] + 2.0)) : 1.f;
    #pragma unroll
    for (int j = 0; j < 4; ++j) {
      long gn = col0 + tc * 4 + j;
      if (gn < N) {
        float v0 = (float)acc[i][j];
        float v = v0 * sc;
        C[gm * ldc + gn] = v;
        if (ZT) {
          u16 hi, mi, lo; split3(v, hi, mi, lo);
          ZT[((long)0 * 208 + gn) * M + gm] = hi;
          ZT[((long)1 * 208 + gn) * M + gm] = mi;
          ZT[((long)2 * 208 + gn) * M + gm] = lo;
        }
      }
    }
  }
}

// ---------- small kernels ----------
struct UpBatch {
  const void* src[19];
  float* dst[19];
  int n[19];
};

__global__ void upcast_batch_k(UpBatch ub, const int* __restrict__ dtf) {
  int bf = *dtf;
  int a = blockIdx.y;
  int i = blockIdx.x * 256 + threadIdx.x;
  if (i < ub.n[a]) ub.dst[a][i] = ld1(ub.src[a], bf, i);
}

// register/shuffle bitonic top-k; emits perm + inverse perm
template<int V>
__global__ __launch_bounds__(1024) void topk_fast(const float* __restrict__ score,
                                                  int n, int np2, int k,
                                                  int* __restrict__ perm,
                                                  int* __restrict__ inv) {
  __shared__ u64 keys[4096];
  const int tid = threadIdx.x;
  const int REGMAX = 32 * V;
  for (int i = tid; i < n; i += 1024) inv[i] = -1;
  u64 kreg[V];
  #pragma unroll
  for (int r = 0; r < V; ++r) {
    int i = tid * V + r;
    u64 key = 0ULL;
    if (i < n) {
      u32 b = __float_as_uint(score[i]);
      u32 u = (b & 0x80000000u) ? ~b : (b | 0x80000000u);
      key = ((u64)u << 32) | (u32)(~(u32)i);
    }
    kreg[r] = key;
  }

  for (int size = 2; size <= np2; size <<= 1) {
    int stride = size >> 1;
    if (stride > REGMAX) {
      #pragma unroll
      for (int r = 0; r < V; ++r) keys[tid * V + r] = kreg[r];
      __syncthreads();
      for (; stride > REGMAX; stride >>= 1) {
        for (int i = tid; i < np2; i += 1024) {
          int j = i ^ stride;
          if (j > i) {
            u64 a = keys[i], b = keys[j];
            bool up = ((i & size) == 0);
            if (up ? (a > b) : (a < b)) { keys[i] = b; keys[j] = a; }
          }
        }
        __syncthreads();
      }
      #pragma unroll
      for (int r = 0; r < V; ++r) kreg[r] = keys[tid * V + r];
    }
    for (; stride >= 1; stride >>= 1) {
      if (stride >= V) {
        int lm = stride / V;
        #pragma unroll
        for (int r = 0; r < V; ++r) {
          u64 mine = kreg[r];
          u64 other = (u64)__shfl_xor((long long)mine, lm);
          int i = tid * V + r;
          bool up = ((i & size) == 0);
          bool lower = ((i & stride) == 0);
          u64 mn = mine < other ? mine : other;
          u64 mx = mine < other ? other : mine;
          kreg[r] = (lower == up) ? mn : mx;
        }
      } else {
        #pragma unroll
        for (int r = 0; r < V; ++r) {
          int pr = r ^ stride;
          if (pr > r) {
            int i = tid * V + r;
            bool up = ((i & size) == 0);
            u64 a = kreg[r], b = kreg[pr];
            if (up ? (a > b) : (a < b)) { kreg[r] = b; kreg[pr] = a; }
          }
        }
      }
    }
  }
  #pragma unroll
  for (int r = 0; r < V; ++r) {
    int i = tid * V + r;
    int rank = np2 - 1 - i;
    if (rank < k) {
      int idx = (int)(~(u32)(kreg[r] & 0xFFFFFFFFull));
      perm[rank] = idx;
      inv[idx] = rank;
    }
  }
}

// fused copy + scatter-add + 3-plane XP emit: dst = xs + upscatter(xpool)
__global__ void upadd_k(const float* __restrict__ xs, const float* __restrict__ xpool,
                        const int* __restrict__ inv, float* __restrict__ dst,
                        u16* __restrict__ XP, int n) {
  long idx = (long)blockIdx.x * 256 + threadIdx.x;
  long tot = (long)n * 224;
  if (idx >= tot) return;
  int i = (int)(idx / 224);
  int c = (int)(idx - (long)i * 224);
  float v = 0.f;
  if (c < 200) {
    v = xs[(long)i * 200 + c];
    int r = inv[i];
    if (r >= 0) v += xpool[(long)r * 200 + c];
    dst[(long)i * 200 + c] = v;
  }
  u16 h, mi, lo; split3(v, h, mi, lo);
  long pitch = (long)n * 224;
  XP[idx] = h; XP[pitch + idx] = mi; XP[2 * pitch + idx] = lo;
}

// fused matvec2 + log-softmax output
__global__ void matvec2_final_k(const void* __restrict__ A, int abf, int n,
                                const float* __restrict__ Zs, const double* __restrict__ rs0,
                                const float* __restrict__ b2, float* __restrict__ out,
                                const int* __restrict__ dtf) {
  const int bf = get_bf(abf, dtf);
  int row = blockIdx.x, tid = threadIdx.x;
  const long base = (long)row * n;
  double s0 = 0.0, s1 = 0.0;
  for (int j = tid; j < n; j += 256) {
    double a = (double)ld1(A, bf, base + j);
    s0 += a * (double)Zs[2 * j];
    s1 += a * (double)Zs[2 * j + 1];
  }
  __shared__ double r0[256], r1[256];
  r0[tid] = s0; r1[tid] = s1; __syncthreads();
  for (int st = 128; st > 0; st >>= 1) {
    if (tid < st) { r0[tid] += r0[tid + st]; r1[tid] += r1[tid + st]; }
    __syncthreads();
  }
  if (tid == 0) {
    double y0 = (double)((float)r0[0]);
    double y1 = (double)((float)r1[0]);
    double di = (double)((float)(1.0 / sqrt(rs0[row] + 2.0)));
    double t0 = di * (y0 + 2.0 * (double)Zs[2 * row]) + (double)b2[0];
    double t1 = di * (y1 + 2.0 * (double)Zs[2 * row + 1]) + (double)b2[1];
    double mx = fmax(t0, t1);
    double l = mx + log(exp(t0 - mx) + exp(t1 - mx));
    out[2 * row] = (float)(t0 - l);
    out[2 * row + 1] = (float)(t1 - l);
  }
}

// ---------- host orchestration ----------
extern "C" void kernel_launch(void* const* d_in, const int* in_sizes, int n_in,
                              void* d_out, int out_size, void* d_ws, size_t ws_size,
                              hipStream_t stream) {
  const int N0 = 4096, H = 200;
  const int K1 = 3072, K2 = 1536, K3 = 768;
  const long WTELEMS = (long)3 * 208 * 224;  // u16 elements per weight

  const void* in_x = d_in[0];
  const void* adj  = d_in[1];
  const void* w0 = d_in[2];  const void* b0 = d_in[3];
  const void* w1 = d_in[4];  const void* b1 = d_in[5];
  const void* w2 = d_in[6];  const void* b2 = d_in[7];
  const void* w3 = d_in[8];  const void* b3 = d_in[9];
  const void* p1 = d_in[10]; const void* p2 = d_in[11];
  const void* p3 = d_in[12];
  const void* u0w = d_in[13]; const void* u0b = d_in[14];
  const void* u1w = d_in[15]; const void* u1b = d_in[16];
  const void* u2w = d_in[17]; const void* u2b = d_in[18];

  char* wp = (char*)d_ws;
  auto alloc = [&](size_t bytes) -> void* {
    void* p = (void*)wp;
    wp += (bytes + 255) & ~(size_t)255;
    return p;
  };
  size_t scrBytes = (size_t)36864 * 208 * 4 + 1024;          // Agb i8 / parts
  void* scratchU = alloc(scrBytes);
  s8*    Agb  = (s8*)scratchU;
  float* parts = (float*)scratchU;
  u16* Ag3h = (u16*)alloc((size_t)K3 * K2 * 2);
  u16* Ag3l = (u16*)alloc((size_t)K3 * K2 * 2);
  u16* Ah0 = (u16*)alloc((size_t)N0 * N0 * 2);
  u16* Ah1 = (u16*)alloc((size_t)K1 * K1 * 2);
  u16* Ah2 = (u16*)alloc((size_t)K2 * K2 * 2);
  u16* Al2 = (u16*)alloc((size_t)K2 * K2 * 2);
  u16* Ah3 = (u16*)alloc((size_t)K3 * K3 * 2);
  u16* Al3 = (u16*)alloc((size_t)K3 * K3 * 2);
  u16* ZT  = (u16*)alloc((size_t)3 * 208 * N0 * 2);
  u16* XP  = (u16*)alloc((size_t)3 * N0 * 224 * 2);          // 5.5 MB x-planes
  u16* WTP = (u16*)alloc((size_t)5 * WTELEMS * 2);           // w1,w2,w3,u0w,u1w
  float* xs0  = (float*)alloc((size_t)N0 * H * 4);
  float* xs1  = (float*)alloc((size_t)K1 * H * 4);
  float* xs2  = (float*)alloc((size_t)K2 * H * 4);
  float* xcur = (float*)alloc((size_t)N0 * H * 4);
  float* xtmp = (float*)alloc((size_t)N0 * H * 4);
  float* Zbuf = (float*)alloc((size_t)N0 * H * 4);
  float* Xinf = (float*)alloc((size_t)N0 * 3 * 4);
  double* rs0 = (double*)alloc((size_t)N0 * 8);
  double* rs1 = (double*)alloc((size_t)K1 * 8);   // rs1..rs3 + dtflag contiguous, zeroed together
  double* rs2 = (double*)alloc((size_t)K2 * 8);
  double* rs3 = (double*)alloc((size_t)K3 * 8);
  int* dtflag = (int*)alloc(256);
  float* scores = (float*)alloc((size_t)N0 * 4);
  int* perm1 = (int*)alloc((size_t)K1 * 4);
  int* perm2 = (int*)alloc((size_t)K2 * 4);
  int* perm3 = (int*)alloc((size_t)K3 * 4);
  int* inv1 = (int*)alloc((size_t)N0 * 4);
  int* inv2 = (int*)alloc((size_t)K1 * 4);
  int* inv3 = (int*)alloc((size_t)K2 * 4);
  float* w0f = (float*)alloc(3 * H * 4);  float* b0f = (float*)alloc(H * 4);
  float* w1f = (float*)alloc(H * H * 4);  float* b1f = (float*)alloc(H * 4);
  float* w2f = (float*)alloc(H * H * 4);  float* b2f = (float*)alloc(H * 4);
  float* w3f = (float*)alloc(H * H * 4);  float* b3f = (float*)alloc(H * 4);
  float* p1f = (float*)alloc(H * 4);
  float* p2f = (float*)alloc(H * 4);
  float* p3f = (float*)alloc(H * 4);
  float* u0wf = (float*)alloc(H * H * 4); float* u0bf = (float*)alloc(H * 4);
  float* u1wf = (float*)alloc(H * H * 4); float* u1bf = (float*)alloc(H * 4);
  float* u2wf = (float*)alloc(H * 2 * 4); float* u2bf = (float*)alloc(2 * 4);
  (void)in_sizes; (void)n_in; (void)out_size; (void)ws_size;

  // zero rs1..rs3 + dtflag in one memset (contiguous, 256B multiples)
  hipMemsetAsync(rs1, 0, (size_t)(K1 + K2 + K3) * 8 + 256, stream);
  detect_k<<<dim3(4096), dim3(256), 0, stream>>>((const u32*)adj, (long)N0 * N0 / 2, dtflag);

  {
    UpBatch ub;
    const void* srcs[19] = {in_x, w0, b0, w1, b1, w2, b2, w3, b3, p1, p2, p3,
                            u0w, u0b, u1w, u1b, u2w, u2b, u2b};
    float* dsts[19] = {Xinf, w0f, b0f, w1f, b1f, w2f, b2f, w3f, b3f, p1f, p2f, p3f,
                       u0wf, u0bf, u1wf, u1bf, u2wf, u2bf, u2bf};
    int ns[19] = {N0 * 3, 3 * H, H, H * H, H, H * H, H, H * H, H, H, H, H,
                  H * H, H, H * H, H, H * 2, 2, 2};
    for (int i = 0; i < 19; ++i) { ub.src[i] = srcs[i]; ub.dst[i] = dsts[i]; ub.n[i] = ns[i]; }
    upcast_batch_k<<<dim3((N0 * 3 + 255) / 256, 19), dim3(256), 0, stream>>>(ub, dtflag);
  }

  // W^T 3-plane splits (w1,w2,w3,u0w,u1w) — pointers passed by value (graph-safe)
  {
    WPtrs wps;
    wps.w[0] = w1f; wps.w[1] = w2f; wps.w[2] = w3f; wps.w[3] = u0wf; wps.w[4] = u1wf;
    wsplit_k<<<dim3((208 * 224 + 255) / 256, 5), dim3(256), 0, stream>>>(wps, WTP);
  }
  u16* WT1  = WTP + 0 * WTELEMS;
  u16* WT2  = WTP + 1 * WTELEMS;
  u16* WT3  = WTP + 2 * WTELEMS;
  u16* WTu0 = WTP + 3 * WTELEMS;
  u16* WTu1 = WTP + 4 * WTELEMS;

  a_from_adj_rs_k<<<dim3(N0), dim3(256), 0, stream>>>(adj, dtflag, N0, Ah0, rs0);

  auto gemm64 = [&](const void* A, long lda, int abf, const void* B, long ldb, int bbf,
                    float* C, long ldc, int M, int Nn, int K, const double* rsum, u16* zt) {
    dim3 g((Nn + 63) / 64, (M + 63) / 64);
    gemm64_f64<<<g, dim3(256), 0, stream>>>(A, lda, abf, B, ldb, bbf, C, ldc, M, Nn, K,
                                            rsum, zt, dtflag);
  };

  // shared gcn tail: agg + reduce/epilogue (+score)
  auto gcn_tail = [&](const u16* Ah, const u16* Al, int n, int chunks, const double* rs,
                      const float* bb, float* out, const float* pwf, float* scoreOut) {
    agg_mfma<13><<<dim3(n / 128, chunks), dim3(256), 0, stream>>>(
        Ah, Al, ZT, parts, n, (n / 32) / chunks);
    reduce_epi_k<<<dim3(n), dim3(256), 0, stream>>>(
        parts, Zbuf, rs, bb, out, n, chunks, 1, pwf, scoreOut);
  };
  // MFMA gcn: Z from XP planes @ WT planes
  auto gcn_mfma = [&](const u16* Ah, const u16* Al, int n, int chunks, const double* rs,
                      const u16* WT, const float* bb, float* out,
                      const float* pwf, float* scoreOut) {
    gemm_xw_mfma<<<dim3(n / 128), dim3(256), 0, stream>>>(XP, WT, rs, Zbuf, ZT, n);
    gcn_tail(Ah, Al, n, chunks, rs, bb, out, pwf, scoreOut);
  };

  // ---------------- forward ----------------
  // gcn0 (K=3, f64 path)
  gemm64(Xinf, 3, 0, w0f, H, 0, Zbuf, H, N0, H, 3, rs0, ZT);
  gcn_tail(Ah0, nullptr, N0, 8, rs0, b0f, xs0, p1f, scores);

  // down 0
  topk_fast<4><<<dim3(1), dim3(1024), 0, stream>>>(scores, N0, 4096, K1, perm1, inv1);
  {
    unsigned nbB = (unsigned)(((long)K1 * N0 + 255) / 256);
    unsigned nbG = (unsigned)(((long)K1 * 224 + 255) / 256);
    bg_i8_k<<<dim3(nbB + nbG), dim3(256), 0, stream>>>(
        adj, -1, N0, perm1, K1, Agb, dtflag, xs0, scores, XP, nbB);
    int nt = K1 / 128;
    syrk_tri_i8<<<dim3(nt * (nt + 1) / 2), dim3(256), 0, stream>>>(
        Agb, N0, K1, N0, Ah1, nullptr, rs1);
  }
  gcn_mfma(Ah1, nullptr, K1, 12, rs1, WT1, b1f, xs1, p2f, scores);

  // down 1
  topk_fast<4><<<dim3(1), dim3(1024), 0, stream>>>(scores, K1, 4096, K2, perm2, inv2);
  {
    unsigned nbB = (unsigned)(((long)K2 * K1 + 255) / 256);
    unsigned nbG = (unsigned)(((long)K2 * 224 + 255) / 256);
    bg_i8_k<<<dim3(nbB + nbG), dim3(256), 0, stream>>>(
        Ah1, 1, K1, perm2, K2, Agb, dtflag, xs1, scores, XP, nbB);
    int nt = K2 / 128;
    syrk_tri_i8<<<dim3(nt * (nt + 1) / 2), dim3(256), 0, stream>>>(
        Agb, K1, K2, K1, Ah2, Al2, rs2);
  }
  gcn_mfma(Ah2, Al2, K2, 24, rs2, WT2, b2f, xs2, p3f, scores);

  // down 2
  topk_fast<2><<<dim3(1), dim3(1024), 0, stream>>>(scores, K2, 2048, K3, perm3, inv3);
  {
    unsigned nbB = (unsigned)(((long)K3 * K2 + 255) / 256);
    unsigned nbG = (unsigned)(((long)K3 * 224 + 255) / 256);
    bg_sp_k<<<dim3(nbB + nbG), dim3(256), 0, stream>>>(
        Ah2, Al2, K2, perm3, K3, Ag3h, Ag3l, xs2, scores, XP, nbB);
    int nt = K3 / 128;
    syrk_tri2_parts<<<dim3(nt * (nt + 1) / 2, 8), dim3(256), 0, stream>>>(
        Ag3h, Ag3l, K2, parts, K3, K2 / 8);
    long nn = (long)K3 * K3;
    reduce_tri_mirror_k<<<dim3((unsigned)(nn / 256)), dim3(256), 0, stream>>>(
        parts, Ah3, Al3, rs3, K3, 8);
  }
  gcn_mfma(Ah3, Al3, K3, 24, rs3, WT3, b3f, xcur, nullptr, nullptr);

  // up 0: j=2
  upadd_k<<<dim3((unsigned)(((long)K2 * 224 + 255) / 256)), dim3(256), 0, stream>>>(
      xs2, xcur, inv3, xtmp, XP, K2);
  gcn_mfma(Ah2, Al2, K2, 24, rs2, WTu0, u0bf, xcur, nullptr, nullptr);

  // up 1: j=1
  upadd_k<<<dim3((unsigned)(((long)K1 * 224 + 255) / 256)), dim3(256), 0, stream>>>(
      xs1, xcur, inv2, xtmp, XP, K1);
  gcn_mfma(Ah1, nullptr, K1, 12, rs1, WTu1, u1bf, xcur, nullptr, nullptr);

  // up 2: j=0 (final, f64)
  upadd_k<<<dim3((unsigned)(((long)N0 * 224 + 255) / 256)), dim3(256), 0, stream>>>(
      xs0, xcur, inv1, xtmp, XP, N0);
  gemm64(xtmp, H, 0, u2wf, 2, 0, Zbuf, 2, N0, 2, H, rs0, nullptr);
  matvec2_final_k<<<dim3(N0), dim3(256), 0, stream>>>(
      adj, -1, N0, Zbuf, rs0, u2bf, (float*)d_out, dtflag);
}

// Round 13
// 935.339 us; speedup vs baseline: 1.1543x; 1.1543x over previous
//
#include <hip/hip_runtime.h>

typedef unsigned short u16;
typedef unsigned int u32;
typedef unsigned long long u64;
typedef signed char s8;
typedef __attribute__((ext_vector_type(8))) short bfrag8;
typedef __attribute__((ext_vector_type(4))) float f32x4;
typedef __attribute__((ext_vector_type(4))) int i32x4;
typedef __attribute__((address_space(1))) const void gconst_void;
typedef __attribute__((address_space(3))) void lds_void_t;

// ---------- helpers ----------
__device__ __forceinline__ float bf2f(u16 u) {
  return __uint_as_float(((u32)u) << 16);
}
__device__ __forceinline__ u16 f2bf(float f) {
  u32 u = __float_as_uint(f);
  u32 r = (u + 0x7FFFu + ((u >> 16) & 1u)) >> 16;  // RTNE
  return (u16)r;
}
__device__ __forceinline__ void split3(float v, u16& hi, u16& mi, u16& lo) {
  hi = f2bf(v); float r1 = v - bf2f(hi);
  mi = f2bf(r1); float r2 = r1 - bf2f(mi);
  lo = f2bf(r2);
}
__device__ __forceinline__ float ld1(const void* p, int isbf, long idx) {
  return isbf ? bf2f(((const u16*)p)[idx]) : ((const float*)p)[idx];
}
__device__ __forceinline__ void ld4(const void* p, int isbf, long base, long gc, long bound, float v[4]) {
  if (gc + 3 < bound && ((base & 3) == 0)) {
    if (isbf) {
      const ushort4 u = *(const ushort4*)((const u16*)p + base);
      v[0] = bf2f(u.x); v[1] = bf2f(u.y); v[2] = bf2f(u.z); v[3] = bf2f(u.w);
    } else {
      const float4 f = *(const float4*)((const float*)p + base);
      v[0] = f.x; v[1] = f.y; v[2] = f.z; v[3] = f.w;
    }
  } else {
    #pragma unroll
    for (int d = 0; d < 4; ++d) v[d] = (gc + d < bound) ? ld1(p, isbf, base + d) : 0.f;
  }
}

// ---------- input dtype autodetect ----------
__global__ void detect_k(const u32* __restrict__ a, long nw, int* __restrict__ flag) {
  long stride = (long)gridDim.x * 256;
  int f = 0;
  for (long j = (long)blockIdx.x * 256 + threadIdx.x; j < nw; j += stride) {
    u32 w = a[j];
    if (w == 0x00003F80u || w == 0x3F803F80u) f = 1;
  }
  if (__any(f)) {
    if ((threadIdx.x & 63) == 0) atomicOr(flag, 1);
  }
}

__device__ __forceinline__ int get_bf(int abf, const int* dtf) {
  return (abf >= 0) ? abf : *dtf;
}

// ---------- async global->LDS stage ----------
__device__ __forceinline__ void stageB16(const void* g, void* lds) {
#if __has_builtin(__builtin_amdgcn_global_load_lds)
  __builtin_amdgcn_global_load_lds((gconst_void*)g, (lds_void_t*)lds, 16, 0, 0);
#else
  int lane = threadIdx.x & 63;
  *(int4*)((char*)lds + lane * 16) = *(const int4*)g;
#endif
}

// ---------- i8 triangle SYRK -> bf16 planes + f64 row sums ----------
__global__ __launch_bounds__(256) void syrk_tri_i8(
    const s8* __restrict__ Ag, int ldk, int ldc, int K,
    u16* __restrict__ Ah, u16* __restrict__ Al, double* __restrict__ rsum)
{
  __shared__ s8 At[128 * 64];
  __shared__ s8 Bt[128 * 64];
  __shared__ int tb[4][16][17];
  const int t = blockIdx.x;
  int ti = (int)((sqrtf((float)(8 * t + 1)) - 1.0f) * 0.5f);
  while ((ti + 1) * (ti + 2) / 2 <= t) ++ti;
  while (ti * (ti + 1) / 2 > t) --ti;
  const int tj = t - ti * (ti + 1) / 2;

  const int tid = threadIdx.x;
  const int wave = tid >> 6, lane = tid & 63;
  const int wr = wave >> 1, wc = wave & 1;
  const long rowA0 = (long)ti * 128;
  const long rowB0 = (long)tj * 128;

  i32x4 acc[4][4];
  #pragma unroll
  for (int i = 0; i < 4; ++i)
    #pragma unroll
    for (int j = 0; j < 4; ++j) acc[i][j] = (i32x4)0;

  const int srow = lane >> 2;
  const int scol = (lane & 3) * 16;
  const int m = lane & 15, q = lane >> 4;

  for (int k0 = 0; k0 < K; k0 += 64) {
    #pragma unroll
    for (int tt = 0; tt < 2; ++tt) {
      const int r = wave * 32 + tt * 16;
      stageB16(Ag + (rowA0 + r + srow) * (long)ldk + k0 + scol, At + r * 64);
      stageB16(Ag + (rowB0 + r + srow) * (long)ldk + k0 + scol, Bt + r * 64);
    }
    __syncthreads();

    i32x4 af[4], bf[4];
    #pragma unroll
    for (int mt = 0; mt < 4; ++mt)
      af[mt] = *(const i32x4*)(At + (wr * 64 + mt * 16 + m) * 64 + q * 16);
    #pragma unroll
    for (int nt = 0; nt < 4; ++nt)
      bf[nt] = *(const i32x4*)(Bt + (wc * 64 + nt * 16 + m) * 64 + q * 16);
    #pragma unroll
    for (int mt = 0; mt < 4; ++mt)
      #pragma unroll
      for (int nt = 0; nt < 4; ++nt)
        acc[mt][nt] = __builtin_amdgcn_mfma_i32_16x16x64_i8(af[mt], bf[nt], acc[mt][nt], 0, 0, 0);
    __syncthreads();
  }

  #pragma unroll
  for (int mt = 0; mt < 4; ++mt) {
    double rp[4] = {0.0, 0.0, 0.0, 0.0};
    #pragma unroll
    for (int nt = 0; nt < 4; ++nt) {
      const long gr0 = rowA0 + wr * 64 + mt * 16 + q * 4;
      const long gc = rowB0 + wc * 64 + nt * 16 + m;
      #pragma unroll
      for (int r = 0; r < 4; ++r) {
        const long gr = gr0 + r;
        int iv = (gr == gc) ? 0 : acc[mt][nt][r];
        float fv = (float)iv;
        long idx = gr * ldc + gc;
        u16 h = f2bf(fv);
        Ah[idx] = h;
        if (Al) Al[idx] = f2bf(fv - bf2f(h));
        rp[r] += (double)iv;
      }
    }
    #pragma unroll
    for (int r = 0; r < 4; ++r) {
      double v = rp[r];
      for (int off = 8; off > 0; off >>= 1) v += __shfl_down(v, off);
      if (m == 0) atomicAdd(&rsum[rowA0 + wr * 64 + mt * 16 + q * 4 + r], v);
    }
  }
  if (ti != tj) {
    #pragma unroll
    for (int nt = 0; nt < 4; ++nt) {
      double cp = 0.0;
      #pragma unroll
      for (int mt = 0; mt < 4; ++mt) {
        #pragma unroll
        for (int r = 0; r < 4; ++r) tb[wave][q * 4 + r][m] = acc[mt][nt][r];
        const long baseR = rowB0 + wc * 64 + nt * 16;
        const long baseC = rowA0 + wr * 64 + mt * 16;
        #pragma unroll
        for (int r = 0; r < 4; ++r) {
          float tv = (float)tb[wave][m][q * 4 + r];
          long idx = (baseR + q * 4 + r) * ldc + baseC + m;
          u16 h = f2bf(tv);
          Ah[idx] = h;
          if (Al) Al[idx] = f2bf(tv - bf2f(h));
        }
        #pragma unroll
        for (int r = 0; r < 4; ++r) cp += (double)acc[mt][nt][r];
      }
      double v = cp;
      v += __shfl_down(v, 32);
      v += __shfl_down(v, 16);
      if (q == 0) atomicAdd(&rsum[rowB0 + wc * 64 + nt * 16 + m], v);
    }
  }
}

// ---------- bf16 2-plane triangle SYRK, K-split parts (L3) ----------
__global__ __launch_bounds__(256) void syrk_tri2_parts(
    const u16* __restrict__ Ah, const u16* __restrict__ Al, int ldk,
    float* __restrict__ parts, int n, int per)
{
  __shared__ u16 Ath[128 * 32];
  __shared__ u16 Bth[128 * 32];
  __shared__ u16 Atl[128 * 32];
  __shared__ u16 Btl[128 * 32];
  const int t = blockIdx.x;
  int ti = (int)((sqrtf((float)(8 * t + 1)) - 1.0f) * 0.5f);
  while ((ti + 1) * (ti + 2) / 2 <= t) ++ti;
  while (ti * (ti + 1) / 2 > t) --ti;
  const int tj = t - ti * (ti + 1) / 2;

  const int tid = threadIdx.x;
  const int wave = tid >> 6, lane = tid & 63;
  const int wr = wave >> 1, wc = wave & 1;
  const long rowA0 = (long)ti * 128;
  const long rowB0 = (long)tj * 128;
  const int kbeg = blockIdx.y * per;
  const int kend = kbeg + per;

  f32x4 acc[4][4];
  #pragma unroll
  for (int i = 0; i < 4; ++i)
    #pragma unroll
    for (int j = 0; j < 4; ++j) acc[i][j] = (f32x4)0.f;

  const int srow = lane >> 2;
  const int scol = (lane & 3) * 8;
  const int m = lane & 15, q = lane >> 4;

  for (int k0 = kbeg; k0 < kend; k0 += 32) {
    #pragma unroll
    for (int tt = 0; tt < 2; ++tt) {
      const int r = wave * 32 + tt * 16;
      stageB16(Ah + (rowA0 + r + srow) * (long)ldk + k0 + scol, Ath + r * 32);
      stageB16(Ah + (rowB0 + r + srow) * (long)ldk + k0 + scol, Bth + r * 32);
      stageB16(Al + (rowA0 + r + srow) * (long)ldk + k0 + scol, Atl + r * 32);
      stageB16(Al + (rowB0 + r + srow) * (long)ldk + k0 + scol, Btl + r * 32);
    }
    __syncthreads();

    bfrag8 afh[4], afl[4], bfh[4], bfl[4];
    #pragma unroll
    for (int mt = 0; mt < 4; ++mt) {
      afh[mt] = *(const bfrag8*)(Ath + (wr * 64 + mt * 16 + m) * 32 + q * 8);
      afl[mt] = *(const bfrag8*)(Atl + (wr * 64 + mt * 16 + m) * 32 + q * 8);
    }
    #pragma unroll
    for (int nt = 0; nt < 4; ++nt) {
      bfh[nt] = *(const bfrag8*)(Bth + (wc * 64 + nt * 16 + m) * 32 + q * 8);
      bfl[nt] = *(const bfrag8*)(Btl + (wc * 64 + nt * 16 + m) * 32 + q * 8);
    }
    #pragma unroll
    for (int mt = 0; mt < 4; ++mt)
      #pragma unroll
      for (int nt = 0; nt < 4; ++nt) {
        acc[mt][nt] = __builtin_amdgcn_mfma_f32_16x16x32_bf16(afh[mt], bfh[nt], acc[mt][nt], 0, 0, 0);
        acc[mt][nt] = __builtin_amdgcn_mfma_f32_16x16x32_bf16(afh[mt], bfl[nt], acc[mt][nt], 0, 0, 0);
        acc[mt][nt] = __builtin_amdgcn_mfma_f32_16x16x32_bf16(afl[mt], bfh[nt], acc[mt][nt], 0, 0, 0);
        acc[mt][nt] = __builtin_amdgcn_mfma_f32_16x16x32_bf16(afl[mt], bfl[nt], acc[mt][nt], 0, 0, 0);
      }
    __syncthreads();
  }

  float* P = parts + (long)blockIdx.y * n * n;
  #pragma unroll
  for (int mt = 0; mt < 4; ++mt) {
    #pragma unroll
    for (int nt = 0; nt < 4; ++nt) {
      const long gr0 = rowA0 + wr * 64 + mt * 16 + q * 4;
      const long gc = rowB0 + wc * 64 + nt * 16 + m;
      #pragma unroll
      for (int r = 0; r < 4; ++r)
        P[(gr0 + r) * n + gc] = acc[mt][nt][r];
    }
  }
}

// sum nz parts, mirror, zero diag; Ah/Al write + f64 row sums.
__global__ void reduce_tri_mirror_k(const float* __restrict__ parts,
                                    u16* __restrict__ Ah, u16* __restrict__ Al,
                                    double* __restrict__ rsum, int n, int nz) {
  __shared__ double red[256];
  const int tid = threadIdx.x;
  long idx = (long)blockIdx.x * 256 + tid;
  long nn = (long)n * n;
  long r = idx / n, c = idx - r * n;
  double myv = 0.0;
  if (idx < nn) {
    if (r == c) {
      Ah[idx] = 0; Al[idx] = 0;
    } else if (r > c) {
      float s = 0.f;
      for (int z = 0; z < nz; ++z) s += parts[(long)z * nn + r * n + c];
      long mi = c * n + r;
      u16 h = f2bf(s);
      u16 l = f2bf(s - bf2f(h));
      Ah[idx] = h; Al[idx] = l;
      Ah[mi] = h;  Al[mi] = l;
      myv = (double)s;
      atomicAdd(&rsum[c], (double)s);
    }
  }
  red[tid] = myv;
  __syncthreads();
  for (int st = 128; st > 0; st >>= 1) {
    if (tid < st) red[tid] += red[tid + st];
    __syncthreads();
  }
  if (tid == 0 && idx < nn) atomicAdd(&rsum[r], red[0]);
}

// ---------- fused build (i8 augment operand) + gather-x (fp32) ----------
__global__ void bg_i8_k(const void* __restrict__ src, int srcbf, int nsrc,
                        const int* __restrict__ perm, int kRows,
                        s8* __restrict__ Ag, const int* __restrict__ dtf,
                        const float* __restrict__ xsrc, const float* __restrict__ score,
                        float* __restrict__ xdst, unsigned nbB) {
  if (blockIdx.x < nbB) {
    long tot = (long)kRows * nsrc;
    long idx = (long)blockIdx.x * 256 + threadIdx.x;
    if (idx >= tot) return;
    int r = (int)(idx / nsrc);
    int c = (int)(idx - (long)r * nsrc);
    int p = perm[r];
    float v = ld1(src, get_bf(srcbf, dtf), (long)p * nsrc + c);
    if (c == p) v += 1.f;
    Ag[idx] = (s8)(int)v;
  } else {
    long tot = (long)kRows * 200;
    long idx = (long)(blockIdx.x - nbB) * 256 + threadIdx.x;
    if (idx >= tot) return;
    int r = (int)(idx / 200);
    int c = (int)(idx - (long)r * 200);
    int p = perm[r];
    xdst[idx] = xsrc[(long)p * 200 + c] * score[p];
  }
}

// fused build (2-plane bf16 from Ah2/Al2) + gather-x (fp32)
__global__ void bg_sp_k(const u16* __restrict__ srcH, const u16* __restrict__ srcL,
                        int nsrc, const int* __restrict__ perm, int kRows,
                        u16* __restrict__ Agh, u16* __restrict__ Agl,
                        const float* __restrict__ xsrc, const float* __restrict__ score,
                        float* __restrict__ xdst, unsigned nbB) {
  if (blockIdx.x < nbB) {
    long tot = (long)kRows * nsrc;
    long idx = (long)blockIdx.x * 256 + threadIdx.x;
    if (idx >= tot) return;
    int r = (int)(idx / nsrc);
    int c = (int)(idx - (long)r * nsrc);
    int p = perm[r];
    long si = (long)p * nsrc + c;
    float v = bf2f(srcH[si]) + bf2f(srcL[si]);  // exact integer reconstruction
    if (c == p) v += 1.f;
    u16 h = f2bf(v);
    Agh[idx] = h;
    Agl[idx] = f2bf(v - bf2f(h));
  } else {
    long tot = (long)kRows * 200;
    long idx = (long)(blockIdx.x - nbB) * 256 + threadIdx.x;
    if (idx >= tot) return;
    int r = (int)(idx / 200);
    int c = (int)(idx - (long)r * 200);
    int p = perm[r];
    xdst[idx] = xsrc[(long)p * 200 + c] * score[p];
  }
}

// ---------- MFMA aggregation: Y = A @ Z ----------
template<int NT>
__global__ __launch_bounds__(256) void agg_mfma(
    const u16* __restrict__ Ah, const u16* __restrict__ Al,
    const u16* __restrict__ ZT, float* __restrict__ parts,
    int K, int per_steps)
{
  __shared__ u16 At[128 * 32];
  __shared__ u16 Alt[128 * 32];
  __shared__ u16 Zt[3 * NT * 512];
  const int tid = threadIdx.x;
  const int wave = tid >> 6, lane = tid & 63;
  const long row0 = (long)blockIdx.x * 128;
  const int chunk = blockIdx.y;
  const int kbeg = chunk * per_steps * 32;
  const int kend = min(K, kbeg + per_steps * 32);
  const int m = lane & 15, q = lane >> 4;
  const int srow = lane >> 2, scol = (lane & 3) * 8;
  const bool hasAl = (Al != nullptr);

  f32x4 acc[2][NT];
  #pragma unroll
  for (int rt = 0; rt < 2; ++rt)
    #pragma unroll
    for (int ct = 0; ct < NT; ++ct) acc[rt][ct] = (f32x4)0.f;

  for (int k0 = kbeg; k0 < kend; k0 += 32) {
    #pragma unroll
    for (int t = 0; t < 2; ++t) {
      const int r = wave * 32 + t * 16;
      stageB16(Ah + (row0 + r + srow) * (long)K + k0 + scol, At + r * 32);
      if (hasAl)
        stageB16(Al + (row0 + r + srow) * (long)K + k0 + scol, Alt + r * 32);
    }
    for (int s = wave; s < 3 * NT; s += 4) {
      const u16* g = ZT + ((long)(s * 16 + srow)) * K + k0 + scol;
      stageB16(g, Zt + s * 512);
    }
    __syncthreads();

    bfrag8 af0 = *(const bfrag8*)(At + (wave * 32 + m) * 32 + q * 8);
    bfrag8 af1 = *(const bfrag8*)(At + (wave * 32 + 16 + m) * 32 + q * 8);
    bfrag8 al0, al1;
    if (hasAl) {
      al0 = *(const bfrag8*)(Alt + (wave * 32 + m) * 32 + q * 8);
      al1 = *(const bfrag8*)(Alt + (wave * 32 + 16 + m) * 32 + q * 8);
    }
    #pragma unroll
    for (int ct = 0; ct < NT; ++ct) {
      bfrag8 b0 = *(const bfrag8*)(Zt + (0 * NT + ct) * 512 + m * 32 + q * 8);
      bfrag8 b1 = *(const bfrag8*)(Zt + (1 * NT + ct) * 512 + m * 32 + q * 8);
      bfrag8 b2 = *(const bfrag8*)(Zt + (2 * NT + ct) * 512 + m * 32 + q * 8);
      acc[0][ct] = __builtin_amdgcn_mfma_f32_16x16x32_bf16(af0, b0, acc[0][ct], 0, 0, 0);
      acc[0][ct] = __builtin_amdgcn_mfma_f32_16x16x32_bf16(af0, b1, acc[0][ct], 0, 0, 0);
      acc[0][ct] = __builtin_amdgcn_mfma_f32_16x16x32_bf16(af0, b2, acc[0][ct], 0, 0, 0);
      acc[1][ct] = __builtin_amdgcn_mfma_f32_16x16x32_bf16(af1, b0, acc[1][ct], 0, 0, 0);
      acc[1][ct] = __builtin_amdgcn_mfma_f32_16x16x32_bf16(af1, b1, acc[1][ct], 0, 0, 0);
      acc[1][ct] = __builtin_amdgcn_mfma_f32_16x16x32_bf16(af1, b2, acc[1][ct], 0, 0, 0);
      if (hasAl) {
        acc[0][ct] = __builtin_amdgcn_mfma_f32_16x16x32_bf16(al0, b0, acc[0][ct], 0, 0, 0);
        acc[0][ct] = __builtin_amdgcn_mfma_f32_16x16x32_bf16(al0, b1, acc[0][ct], 0, 0, 0);
        acc[1][ct] = __builtin_amdgcn_mfma_f32_16x16x32_bf16(al1, b0, acc[1][ct], 0, 0, 0);
        acc[1][ct] = __builtin_amdgcn_mfma_f32_16x16x32_bf16(al1, b1, acc[1][ct], 0, 0, 0);
      }
    }
    __syncthreads();
  }

  float* P = parts + (long)chunk * gridDim.x * 128 * (NT * 16);
  #pragma unroll
  for (int rt = 0; rt < 2; ++rt) {
    #pragma unroll
    for (int ct = 0; ct < NT; ++ct) {
      const long grow0 = row0 + wave * 32 + rt * 16 + q * 4;
      const long gcol = ct * 16 + m;
      #pragma unroll
      for (int r = 0; r < 4; ++r)
        P[(grow0 + r) * (NT * 16) + gcol] = acc[rt][ct][r];
    }
  }
}

// fused: reduce parts + GCN epilogue (+ optional pooling score)
__global__ __launch_bounds__(256) void reduce_epi_k(
    const float* __restrict__ parts, const float* __restrict__ Zs,
    const double* __restrict__ rs, const float* __restrict__ b,
    float* __restrict__ out, int n, int nz, int relu,
    const float* __restrict__ pw, float* __restrict__ score)
{
  __shared__ float vrow[200];
  const int i = blockIdx.x, tid = threadIdx.x;
  float dv = (float)(1.0 / sqrt(rs[i] + 2.0));
  if (tid < 200) {
    long base = (long)i * 208 + tid;
    float s = 0.f;
    for (int c = 0; c < nz; ++c) s += parts[(long)c * n * 208 + base];
    float v = dv * (s + 2.f * Zs[(long)i * 200 + tid]) + b[tid];
    if (relu) v = fmaxf(v, 0.f);
    out[(long)i * 200 + tid] = v;
    if (score) vrow[tid] = v;
  }
  if (!score) return;
  __syncthreads();
  if (tid < 64) {
    double ps = 0.0;
    for (int j = tid; j < 200; j += 64) { double w = pw[j]; ps += w * w; }
    for (int off = 32; off > 0; off >>= 1) ps += __shfl_down(ps, off);
    double nrm = sqrt(__shfl(ps, 0));
    double s = 0.0;
    for (int j = tid; j < 200; j += 64) s += (double)vrow[j] * (double)pw[j];
    for (int off = 32; off > 0; off >>= 1) s += __shfl_down(s, off);
    if (tid == 0) score[i] = (float)tanh(s / nrm);
  }
}

// fused adj->bf16 plane + row sums (level 0)
__global__ void a_from_adj_rs_k(const void* __restrict__ adj, const int* __restrict__ dtf,
                                int n, u16* __restrict__ Ah, double* __restrict__ rs) {
  __shared__ double red[256];
  int bf = *dtf;
  const int row = blockIdx.x, tid = threadIdx.x;
  const long base = (long)row * n;
  double s = 0.0;
  for (int j = tid; j < n; j += 256) {
    float v = ld1(adj, bf, base + j);
    Ah[base + j] = bf ? ((const u16*)adj)[base + j] : f2bf(v);
    s += (double)v;
  }
  red[tid] = s; __syncthreads();
  for (int st = 128; st > 0; st >>= 1) {
    if (tid < st) red[tid] += red[tid + st];
    __syncthreads();
  }
  if (tid == 0) rs[row] = red[0];
}

// ---------- fp64 GEMM (x@W) with fused dinv scale + transposed 3-plane ZT split ----------
__global__ __launch_bounds__(256) void gemm64_f64(
    const void* __restrict__ Ap, long lda, int abf,
    const void* __restrict__ Bp, long ldb, int bbf,
    float* __restrict__ C, long ldc, int M, int N, int K,
    const double* __restrict__ rsum, u16* __restrict__ ZT, const int* __restrict__ dtf)
{
  const int abf_ = get_bf(abf, dtf);
  const int bbf_ = get_bf(bbf, dtf);
  __shared__ float As[16][64];
  __shared__ float Bs[16][64];
  const int tid = threadIdx.x;
  const int tr = tid >> 4, tc = tid & 15;
  const long row0 = (long)blockIdx.y * 64;
  const long col0 = (long)blockIdx.x * 64;
  double acc[4][4];
  #pragma unroll
  for (int i = 0; i < 4; ++i)
    #pragma unroll
    for (int j = 0; j < 4; ++j) acc[i][j] = 0.0;

  const int am = tid >> 2;
  const int ak = (tid & 3) * 4;
  const int bk = tid >> 4;
  const int bn = (tid & 15) * 4;

  for (int k0 = 0; k0 < K; k0 += 16) {
    float va[4] = {0.f, 0.f, 0.f, 0.f};
    {
      long gm = row0 + am; long gk = k0 + ak;
      if (gm < M && gk < K) ld4(Ap, abf_, gm * lda + gk, gk, K, va);
    }
    As[ak + 0][am] = va[0]; As[ak + 1][am] = va[1];
    As[ak + 2][am] = va[2]; As[ak + 3][am] = va[3];

    float vb[4] = {0.f, 0.f, 0.f, 0.f};
    {
      long gk = k0 + bk; long gn = col0 + bn;
      if (gk < K && gn < N) ld4(Bp, bbf_, gk * ldb + gn, gn, N, vb);
    }
    Bs[bk][bn + 0] = vb[0]; Bs[bk][bn + 1] = vb[1];
    Bs[bk][bn + 2] = vb[2]; Bs[bk][bn + 3] = vb[3];

    __syncthreads();
    #pragma unroll
    for (int kk = 0; kk < 16; ++kk) {
      float a[4], b[4];
      #pragma unroll
      for (int i = 0; i < 4; ++i) a[i] = As[kk][tr * 4 + i];
      #pragma unroll
      for (int j = 0; j < 4; ++j) b[j] = Bs[kk][tc * 4 + j];
      #pragma unroll
      for (int i = 0; i < 4; ++i)
        #pragma unroll
        for (int j = 0; j < 4; ++j)
          acc[i][j] += (double)a[i] * (double)b[j];
    }
    __syncthreads();
  }
  #pragma unroll
  for (int i = 0; i < 4; ++i) {
    long gm = row0 + tr * 4 + i;
    if (gm >= M) continue;
    float sc = rsum ? (float)(1.0 / sqrt(rsum[gm] + 2.0)) : 1.f;
    #pragma unroll
    for (int j = 0; j < 4; ++j) {
      long gn = col0 + tc * 4 + j;
      if (gn < N) {
        float v0 = (float)acc[i][j];
        float v = v0 * sc;
        C[gm * ldc + gn] = v;
        if (ZT) {
          u16 hi, mi, lo; split3(v, hi, mi, lo);
          ZT[((long)0 * 208 + gn) * M + gm] = hi;
          ZT[((long)1 * 208 + gn) * M + gm] = mi;
          ZT[((long)2 * 208 + gn) * M + gm] = lo;
        }
      }
    }
  }
}

// ---------- small kernels ----------
struct UpBatch {
  const void* src[19];
  float* dst[19];
  int n[19];
};

__global__ void upcast_batch_k(UpBatch ub, const int* __restrict__ dtf) {
  int bf = *dtf;
  int a = blockIdx.y;
  int i = blockIdx.x * 256 + threadIdx.x;
  if (i < ub.n[a]) ub.dst[a][i] = ld1(ub.src[a], bf, i);
}

// register/shuffle bitonic top-k; emits perm + inverse perm
template<int V>
__global__ __launch_bounds__(1024) void topk_fast(const float* __restrict__ score,
                                                  int n, int np2, int k,
                                                  int* __restrict__ perm,
                                                  int* __restrict__ inv) {
  __shared__ u64 keys[4096];
  const int tid = threadIdx.x;
  const int REGMAX = 32 * V;
  for (int i = tid; i < n; i += 1024) inv[i] = -1;
  u64 kreg[V];
  #pragma unroll
  for (int r = 0; r < V; ++r) {
    int i = tid * V + r;
    u64 key = 0ULL;
    if (i < n) {
      u32 b = __float_as_uint(score[i]);
      u32 u = (b & 0x80000000u) ? ~b : (b | 0x80000000u);
      key = ((u64)u << 32) | (u32)(~(u32)i);
    }
    kreg[r] = key;
  }

  for (int size = 2; size <= np2; size <<= 1) {
    int stride = size >> 1;
    if (stride > REGMAX) {
      #pragma unroll
      for (int r = 0; r < V; ++r) keys[tid * V + r] = kreg[r];
      __syncthreads();
      for (; stride > REGMAX; stride >>= 1) {
        for (int i = tid; i < np2; i += 1024) {
          int j = i ^ stride;
          if (j > i) {
            u64 a = keys[i], b = keys[j];
            bool up = ((i & size) == 0);
            if (up ? (a > b) : (a < b)) { keys[i] = b; keys[j] = a; }
          }
        }
        __syncthreads();
      }
      #pragma unroll
      for (int r = 0; r < V; ++r) kreg[r] = keys[tid * V + r];
    }
    for (; stride >= 1; stride >>= 1) {
      if (stride >= V) {
        int lm = stride / V;
        #pragma unroll
        for (int r = 0; r < V; ++r) {
          u64 mine = kreg[r];
          u64 other = (u64)__shfl_xor((long long)mine, lm);
          int i = tid * V + r;
          bool up = ((i & size) == 0);
          bool lower = ((i & stride) == 0);
          u64 mn = mine < other ? mine : other;
          u64 mx = mine < other ? other : mine;
          kreg[r] = (lower == up) ? mn : mx;
        }
      } else {
        #pragma unroll
        for (int r = 0; r < V; ++r) {
          int pr = r ^ stride;
          if (pr > r) {
            int i = tid * V + r;
            bool up = ((i & size) == 0);
            u64 a = kreg[r], b = kreg[pr];
            if (up ? (a > b) : (a < b)) { kreg[r] = b; kreg[pr] = a; }
          }
        }
      }
    }
  }
  #pragma unroll
  for (int r = 0; r < V; ++r) {
    int i = tid * V + r;
    int rank = np2 - 1 - i;
    if (rank < k) {
      int idx = (int)(~(u32)(kreg[r] & 0xFFFFFFFFull));
      perm[rank] = idx;
      inv[idx] = rank;
    }
  }
}

// fused copy + scatter-add via inverse perm: dst = xs + upscatter(xpool)
__global__ void upadd_k(const float* __restrict__ xs, const float* __restrict__ xpool,
                        const int* __restrict__ inv, float* __restrict__ dst, long nh, int h) {
  long idx = (long)blockIdx.x * 256 + threadIdx.x;
  if (idx >= nh) return;
  int i = (int)(idx / h);
  int c = (int)(idx - (long)i * h);
  float v = xs[idx];
  int r = inv[i];
  if (r >= 0) v += xpool[(long)r * h + c];
  dst[idx] = v;
}

// fused matvec2 + log-softmax output
__global__ void matvec2_final_k(const void* __restrict__ A, int abf, int n,
                                const float* __restrict__ Zs, const double* __restrict__ rs0,
                                const float* __restrict__ b2, float* __restrict__ out,
                                const int* __restrict__ dtf) {
  const int bf = get_bf(abf, dtf);
  int row = blockIdx.x, tid = threadIdx.x;
  const long base = (long)row * n;
  double s0 = 0.0, s1 = 0.0;
  for (int j = tid; j < n; j += 256) {
    double a = (double)ld1(A, bf, base + j);
    s0 += a * (double)Zs[2 * j];
    s1 += a * (double)Zs[2 * j + 1];
  }
  __shared__ double r0[256], r1[256];
  r0[tid] = s0; r1[tid] = s1; __syncthreads();
  for (int st = 128; st > 0; st >>= 1) {
    if (tid < st) { r0[tid] += r0[tid + st]; r1[tid] += r1[tid + st]; }
    __syncthreads();
  }
  if (tid == 0) {
    double y0 = (double)((float)r0[0]);
    double y1 = (double)((float)r1[0]);
    double di = (double)((float)(1.0 / sqrt(rs0[row] + 2.0)));
    double t0 = di * (y0 + 2.0 * (double)Zs[2 * row]) + (double)b2[0];
    double t1 = di * (y1 + 2.0 * (double)Zs[2 * row + 1]) + (double)b2[1];
    double mx = fmax(t0, t1);
    double l = mx + log(exp(t0 - mx) + exp(t1 - mx));
    out[2 * row] = (float)(t0 - l);
    out[2 * row + 1] = (float)(t1 - l);
  }
}

// ---------- host orchestration ----------
extern "C" void kernel_launch(void* const* d_in, const int* in_sizes, int n_in,
                              void* d_out, int out_size, void* d_ws, size_t ws_size,
                              hipStream_t stream) {
  const int N0 = 4096, H = 200;
  const int K1 = 3072, K2 = 1536, K3 = 768;

  const void* in_x = d_in[0];
  const void* adj  = d_in[1];
  const void* w0 = d_in[2];  const void* b0 = d_in[3];
  const void* w1 = d_in[4];  const void* b1 = d_in[5];
  const void* w2 = d_in[6];  const void* b2 = d_in[7];
  const void* w3 = d_in[8];  const void* b3 = d_in[9];
  const void* p1 = d_in[10]; const void* p2 = d_in[11];
  const void* p3 = d_in[12];
  const void* u0w = d_in[13]; const void* u0b = d_in[14];
  const void* u1w = d_in[15]; const void* u1b = d_in[16];
  const void* u2w = d_in[17]; const void* u2b = d_in[18];

  char* wp = (char*)d_ws;
  auto alloc = [&](size_t bytes) -> void* {
    void* p = (void*)wp;
    wp += (bytes + 255) & ~(size_t)255;
    return p;
  };
  size_t scrBytes = (size_t)36864 * 208 * 4 + 1024;          // Agb i8 / parts (disjoint)
  void* scratchU = alloc(scrBytes);
  s8*    Agb  = (s8*)scratchU;
  float* parts = (float*)scratchU;
  u16* Ag3h = (u16*)alloc((size_t)K3 * K2 * 2);
  u16* Ag3l = (u16*)alloc((size_t)K3 * K2 * 2);
  u16* Ah0 = (u16*)alloc((size_t)N0 * N0 * 2);
  u16* Ah1 = (u16*)alloc((size_t)K1 * K1 * 2);
  u16* Ah2 = (u16*)alloc((size_t)K2 * K2 * 2);
  u16* Al2 = (u16*)alloc((size_t)K2 * K2 * 2);
  u16* Ah3 = (u16*)alloc((size_t)K3 * K3 * 2);
  u16* Al3 = (u16*)alloc((size_t)K3 * K3 * 2);
  u16* ZT  = (u16*)alloc((size_t)3 * 208 * N0 * 2);
  float* xs0  = (float*)alloc((size_t)N0 * H * 4);
  float* xs1  = (float*)alloc((size_t)K1 * H * 4);
  float* xs2  = (float*)alloc((size_t)K2 * H * 4);
  float* xcur = (float*)alloc((size_t)N0 * H * 4);
  float* xtmp = (float*)alloc((size_t)N0 * H * 4);
  float* Zbuf = (float*)alloc((size_t)N0 * H * 4);
  float* Xinf = (float*)alloc((size_t)N0 * 3 * 4);
  double* rs0 = (double*)alloc((size_t)N0 * 8);
  double* rs1 = (double*)alloc((size_t)K1 * 8);   // rs1..rs3 + dtflag contiguous, one memset
  double* rs2 = (double*)alloc((size_t)K2 * 8);
  double* rs3 = (double*)alloc((size_t)K3 * 8);
  int* dtflag = (int*)alloc(256);
  float* scores = (float*)alloc((size_t)N0 * 4);
  int* perm1 = (int*)alloc((size_t)K1 * 4);
  int* perm2 = (int*)alloc((size_t)K2 * 4);
  int* perm3 = (int*)alloc((size_t)K3 * 4);
  int* inv1 = (int*)alloc((size_t)N0 * 4);
  int* inv2 = (int*)alloc((size_t)K1 * 4);
  int* inv3 = (int*)alloc((size_t)K2 * 4);
  float* w0f = (float*)alloc(3 * H * 4);  float* b0f = (float*)alloc(H * 4);
  float* w1f = (float*)alloc(H * H * 4);  float* b1f = (float*)alloc(H * 4);
  float* w2f = (float*)alloc(H * H * 4);  float* b2f = (float*)alloc(H * 4);
  float* w3f = (float*)alloc(H * H * 4);  float* b3f = (float*)alloc(H * 4);
  float* p1f = (float*)alloc(H * 4);
  float* p2f = (float*)alloc(H * 4);
  float* p3f = (float*)alloc(H * 4);
  float* u0wf = (float*)alloc(H * H * 4); float* u0bf = (float*)alloc(H * 4);
  float* u1wf = (float*)alloc(H * H * 4); float* u1bf = (float*)alloc(H * 4);
  float* u2wf = (float*)alloc(H * 2 * 4); float* u2bf = (float*)alloc(2 * 4);
  (void)in_sizes; (void)n_in; (void)out_size; (void)ws_size;

  // zero rs1..rs3 + dtflag in one memset (contiguous, 256B multiples)
  hipMemsetAsync(rs1, 0, (size_t)(K1 + K2 + K3) * 8 + 256, stream);
  detect_k<<<dim3(4096), dim3(256), 0, stream>>>((const u32*)adj, (long)N0 * N0 / 2, dtflag);

  {
    UpBatch ub;
    const void* srcs[19] = {in_x, w0, b0, w1, b1, w2, b2, w3, b3, p1, p2, p3,
                            u0w, u0b, u1w, u1b, u2w, u2b, u2b};
    float* dsts[19] = {Xinf, w0f, b0f, w1f, b1f, w2f, b2f, w3f, b3f, p1f, p2f, p3f,
                       u0wf, u0bf, u1wf, u1bf, u2wf, u2bf, u2bf};
    int ns[19] = {N0 * 3, 3 * H, H, H * H, H, H * H, H, H * H, H, H, H, H,
                  H * H, H, H * H, H, H * 2, 2, 2};
    for (int i = 0; i < 19; ++i) { ub.src[i] = srcs[i]; ub.dst[i] = dsts[i]; ub.n[i] = ns[i]; }
    upcast_batch_k<<<dim3((N0 * 3 + 255) / 256, 19), dim3(256), 0, stream>>>(ub, dtflag);
  }

  a_from_adj_rs_k<<<dim3(N0), dim3(256), 0, stream>>>(adj, dtflag, N0, Ah0, rs0);

  auto gemm64 = [&](const void* A, long lda, int abf, const void* B, long ldb, int bbf,
                    float* C, long ldc, int M, int Nn, int K, const double* rsum, u16* zt) {
    dim3 g((Nn + 63) / 64, (M + 63) / 64);
    gemm64_f64<<<g, dim3(256), 0, stream>>>(A, lda, abf, B, ldb, bbf, C, ldc, M, Nn, K,
                                            rsum, zt, dtflag);
  };

  // GCN: out = maybe_relu(dinv .* (A@Zs + 2 Zs) + b); optional fused pooling score
  auto gcn = [&](const u16* Ah, const u16* Al, int n, int chunks, const double* rs,
                 const float* Xin_, int din, const float* W, const float* bb,
                 float* out, const float* pwf, float* scoreOut) {
    gemm64(Xin_, din, 0, W, H, 0, Zbuf, H, n, H, din, rs, ZT);  // Z(+scale) + ZT planes
    agg_mfma<13><<<dim3(n / 128, chunks), dim3(256), 0, stream>>>(
        Ah, Al, ZT, parts, n, (n / 32) / chunks);
    reduce_epi_k<<<dim3(n), dim3(256), 0, stream>>>(
        parts, Zbuf, rs, bb, out, n, chunks, 1, pwf, scoreOut);
  };

  // ---------------- forward ----------------
  gcn(Ah0, nullptr, N0, 8, rs0, Xinf, 3, w0f, b0f, xs0, p1f, scores);

  // down 0: i8 SYRK (Ah1 + rowsum only); fused build+gather
  topk_fast<4><<<dim3(1), dim3(1024), 0, stream>>>(scores, N0, 4096, K1, perm1, inv1);
  {
    unsigned nbB = (unsigned)(((long)K1 * N0 + 255) / 256);
    unsigned nbG = (unsigned)(((long)K1 * 200 + 255) / 256);
    bg_i8_k<<<dim3(nbB + nbG), dim3(256), 0, stream>>>(
        adj, -1, N0, perm1, K1, Agb, dtflag, xs0, scores, xcur, nbB);
    int nt = K1 / 128;
    syrk_tri_i8<<<dim3(nt * (nt + 1) / 2), dim3(256), 0, stream>>>(
        Agb, N0, K1, N0, Ah1, nullptr, rs1);
  }
  gcn(Ah1, nullptr, K1, 12, rs1, xcur, H, w1f, b1f, xs1, p2f, scores);

  // down 1: i8 SYRK; source read from bf16 Ah1 (exact ints <= 70)
  topk_fast<4><<<dim3(1), dim3(1024), 0, stream>>>(scores, K1, 4096, K2, perm2, inv2);
  {
    unsigned nbB = (unsigned)(((long)K2 * K1 + 255) / 256);
    unsigned nbG = (unsigned)(((long)K2 * 200 + 255) / 256);
    bg_i8_k<<<dim3(nbB + nbG), dim3(256), 0, stream>>>(
        Ah1, 1, K1, perm2, K2, Agb, dtflag, xs1, scores, xcur, nbB);
    int nt = K2 / 128;
    syrk_tri_i8<<<dim3(nt * (nt + 1) / 2), dim3(256), 0, stream>>>(
        Agb, K1, K2, K1, Ah2, Al2, rs2);
  }
  gcn(Ah2, Al2, K2, 24, rs2, xcur, H, w2f, b2f, xs2, p3f, scores);

  // down 2: bf16 2-plane K-split triangle (Ah3/Al3 + rowsum in reduce)
  topk_fast<2><<<dim3(1), dim3(1024), 0, stream>>>(scores, K2, 2048, K3, perm3, inv3);
  {
    unsigned nbB = (unsigned)(((long)K3 * K2 + 255) / 256);
    unsigned nbG = (unsigned)(((long)K3 * 200 + 255) / 256);
    bg_sp_k<<<dim3(nbB + nbG), dim3(256), 0, stream>>>(
        Ah2, Al2, K2, perm3, K3, Ag3h, Ag3l, xs2, scores, xcur, nbB);
    int nt = K3 / 128;
    syrk_tri2_parts<<<dim3(nt * (nt + 1) / 2, 8), dim3(256), 0, stream>>>(
        Ag3h, Ag3l, K2, parts, K3, K2 / 8);
    long nn = (long)K3 * K3;
    reduce_tri_mirror_k<<<dim3((unsigned)(nn / 256)), dim3(256), 0, stream>>>(
        parts, Ah3, Al3, rs3, K3, 8);
  }
  gcn(Ah3, Al3, K3, 24, rs3, xcur, H, w3f, b3f, xcur, nullptr, nullptr);

  // up 0: j=2
  upadd_k<<<dim3((unsigned)(((long)K2 * H + 255) / 256)), dim3(256), 0, stream>>>(
      xs2, xcur, inv3, xtmp, (long)K2 * H, H);
  gcn(Ah2, Al2, K2, 24, rs2, xtmp, H, u0wf, u0bf, xcur, nullptr, nullptr);

  // up 1: j=1
  upadd_k<<<dim3((unsigned)(((long)K1 * H + 255) / 256)), dim3(256), 0, stream>>>(
      xs1, xcur, inv2, xtmp, (long)K1 * H, H);
  gcn(Ah1, nullptr, K1, 12, rs1, xtmp, H, u1wf, u1bf, xcur, nullptr, nullptr);

  // up 2: j=0 (final, f64)
  upadd_k<<<dim3((unsigned)(((long)N0 * H + 255) / 256)), dim3(256), 0, stream>>>(
      xs0, xcur, inv1, xtmp, (long)N0 * H, H);
  gemm64(xtmp, H, 0, u2wf, 2, 0, Zbuf, 2, N0, 2, H, rs0, nullptr);
  matvec2_final_k<<<dim3(N0), dim3(256), 0, stream>>>(
      adj, -1, N0, Zbuf, rs0, u2bf, (float*)d_out, dtflag);
}